// Round 1
// baseline (2992.499 us; speedup 1.0000x reference)
//
#include <hip/hip_runtime.h>
#include <math.h>

#define NNODES 100000
#define NEDGES 1600000
#define DIM 128
#define NG 64
#define GATE 512
#define CH 16

__device__ __forceinline__ float sigf(float x) { return 1.0f / (1.0f + __expf(-x)); }
__device__ __forceinline__ float tanhfast(float x) {
    float e = __expf(2.0f * x);
    return 1.0f - 2.0f / (e + 1.0f);
}

// degree count by col (in-degree), float atomics
__global__ __launch_bounds__(256) void k_deg(const int* __restrict__ ei, float* __restrict__ deg) {
    int e = blockIdx.x * 256 + threadIdx.x;
    if (e < NEDGES) atomicAdd(&deg[ei[NEDGES + e]], 1.0f);
}

__global__ __launch_bounds__(256) void k_dinv(const float* __restrict__ deg, float* __restrict__ dinv) {
    int n = blockIdx.x * 256 + threadIdx.x;
    if (n < NNODES) dinv[n] = rsqrtf(deg[n] + 1.0f);
}

// y[n] = (x[n] @ W) * dinv[n]; agg2 initialized to y (self-loop term)
__global__ __launch_bounds__(256) void k_gemm(const float* __restrict__ x, const float* __restrict__ W,
                                              const float* __restrict__ dinv,
                                              float* __restrict__ y, float* __restrict__ agg2) {
    __shared__ float4 Wl[DIM * DIM / 4];  // 64 KB
    const float4* W4 = (const float4*)W;
    int tid = threadIdx.x;
#pragma unroll
    for (int l = 0; l < 16; ++l) Wl[tid + l * 256] = W4[tid + l * 256];
    __syncthreads();

    int tr = tid >> 5, tc = tid & 31;  // 8 row-groups x 32 col-groups
    int rb = blockIdx.x * 64;
    const float4* x4 = (const float4*)x;

    int r[8];
    bool valid[8];
#pragma unroll
    for (int i = 0; i < 8; ++i) {
        int rr = rb + tr * 8 + i;
        valid[i] = rr < NNODES;
        r[i] = valid[i] ? rr : (NNODES - 1);
    }

    float4 acc[8];
#pragma unroll
    for (int i = 0; i < 8; ++i) acc[i] = make_float4(0.f, 0.f, 0.f, 0.f);

    for (int k = 0; k < DIM; k += 4) {
        float4 wv[4];
#pragma unroll
        for (int kk = 0; kk < 4; ++kk) wv[kk] = Wl[(k + kk) * 32 + tc];
#pragma unroll
        for (int i = 0; i < 8; ++i) {
            float4 xv = x4[(size_t)r[i] * 32 + (k >> 2)];
            acc[i].x += xv.x * wv[0].x + xv.y * wv[1].x + xv.z * wv[2].x + xv.w * wv[3].x;
            acc[i].y += xv.x * wv[0].y + xv.y * wv[1].y + xv.z * wv[2].y + xv.w * wv[3].y;
            acc[i].z += xv.x * wv[0].z + xv.y * wv[1].z + xv.z * wv[2].z + xv.w * wv[3].z;
            acc[i].w += xv.x * wv[0].w + xv.y * wv[1].w + xv.z * wv[2].w + xv.w * wv[3].w;
        }
    }

    float4* y4 = (float4*)y;
    float4* a4 = (float4*)agg2;
#pragma unroll
    for (int i = 0; i < 8; ++i) {
        if (valid[i]) {
            float dv = dinv[r[i]];
            float4 v = make_float4(acc[i].x * dv, acc[i].y * dv, acc[i].z * dv, acc[i].w * dv);
            y4[(size_t)r[i] * 32 + tc] = v;
            a4[(size_t)r[i] * 32 + tc] = v;
        }
    }
}

// agg2[col] += y[row] for every edge (float atomics)
__global__ __launch_bounds__(256) void k_scatter(const int* __restrict__ ei, const float4* __restrict__ y4,
                                                 float* __restrict__ agg2) {
    int sub = threadIdx.x >> 5;  // 8 edges in parallel
    int l = threadIdx.x & 31;    // 32 lanes x float4 = 128 dims
    long base = (long)blockIdx.x * 32;
#pragma unroll
    for (int t = 0; t < 4; ++t) {
        long e = base + t * 8 + sub;
        if (e < NEDGES) {
            int row = ei[e];
            int col = ei[NEDGES + e];
            float4 v = y4[(size_t)row * 32 + l];
            float* dst = agg2 + (size_t)col * DIM + l * 4;
            atomicAdd(dst + 0, v.x);
            atomicAdd(dst + 1, v.y);
            atomicAdd(dst + 2, v.z);
            atomicAdd(dst + 3, v.w);
        }
    }
}

// graph segment boundaries (batch is sorted)
__global__ void k_bounds(const int* __restrict__ batch, int* __restrict__ start) {
    int g = threadIdx.x;
    if (g <= NG) {
        int lo = 0, hi = NNODES;
        while (lo < hi) {
            int mid = (lo + hi) >> 1;
            if (batch[mid] < g) lo = mid + 1; else hi = mid;
        }
        start[g] = lo;
    }
}

// sums[g][d] = sum over nodes of relu(dinv[n]*agg2[n][d] + b[d])
__global__ __launch_bounds__(128) void k_pool(const float* __restrict__ agg2, const float* __restrict__ dinv,
                                              const float* __restrict__ b, const int* __restrict__ start,
                                              float* __restrict__ sums) {
    int g = blockIdx.x / CH, q = blockIdx.x % CH;
    int d = threadIdx.x;
    int s = start[g], e = start[g + 1];
    int len = e - s;
    int n0 = s + (int)((long)len * q / CH);
    int n1 = s + (int)((long)len * (q + 1) / CH);
    float bias = b[d];
    float acc = 0.f;
    for (int n = n0; n < n1; ++n) {
        float v = dinv[n] * agg2[(size_t)n * DIM + d] + bias;
        acc += fmaxf(v, 0.f);
    }
    atomicAdd(&sums[g * DIM + d], acc);
}

// xg[t][j] = b_ih[j] + b_hh[j] + pooled[t] . w_ih[j]
__global__ __launch_bounds__(512) void k_xgate(const float* __restrict__ sums, const int* __restrict__ start,
                                               const float* __restrict__ w_ih, const float* __restrict__ b_ih,
                                               const float* __restrict__ b_hh, float* __restrict__ xg) {
    __shared__ float4 p4[DIM / 4];
    int t = blockIdx.x, j = threadIdx.x;
    if (j < DIM) {
        int c = start[t + 1] - start[t];
        float inv = 1.0f / fmaxf((float)c, 1.0f);
        ((float*)p4)[j] = sums[t * DIM + j] * inv;
    }
    __syncthreads();
    const float4* w4 = (const float4*)(w_ih + (size_t)j * DIM);
    float acc = b_ih[j] + b_hh[j];
#pragma unroll
    for (int kk = 0; kk < 32; ++kk) {
        float4 w = w4[kk];
        float4 p = p4[kk];
        acc += w.x * p.x + w.y * p.y + w.z * p.z + w.w * p.w;
    }
    xg[t * GATE + j] = acc;
}

// sequential LSTM recurrence + final FC, single block
__global__ __launch_bounds__(1024) void k_lstm(const float* __restrict__ xg, const float* __restrict__ w_hh,
                                               const float* __restrict__ Wfc, const float* __restrict__ bfc,
                                               float* __restrict__ out) {
    __shared__ float h_lds[DIM];
    __shared__ float gates[GATE];
    __shared__ float hs[NG * DIM];  // 32 KB
    int tid = threadIdx.x;
    int j = tid >> 1, half = tid & 1;

    // each thread holds 64 weights of w_hh row j (its half)
    float4 wv[16];
    const float4* w4 = (const float4*)(w_hh + (size_t)j * DIM + half * 64);
#pragma unroll
    for (int kk = 0; kk < 16; ++kk) wv[kk] = w4[kk];

    float c = 0.f;
    if (tid < DIM) h_lds[tid] = 0.f;
    __syncthreads();

    const float4* h4 = (const float4*)h_lds;
    for (int t = 0; t < NG; ++t) {
        float acc = (half == 0) ? xg[t * GATE + j] : 0.f;
#pragma unroll
        for (int kk = 0; kk < 16; ++kk) {
            float4 hv = h4[half * 16 + kk];
            float4 w = wv[kk];
            acc += w.x * hv.x + w.y * hv.y + w.z * hv.z + w.w * hv.w;
        }
        acc += __shfl_xor(acc, 1, 64);
        if (half == 0) gates[j] = acc;
        __syncthreads();
        if (tid < DIM) {
            float gi = gates[tid], gf = gates[DIM + tid], gg = gates[2 * DIM + tid], go = gates[3 * DIM + tid];
            c = sigf(gf) * c + sigf(gi) * tanhfast(gg);
            float hn = sigf(go) * tanhfast(c);
            h_lds[tid] = hn;
            hs[t * DIM + tid] = hn;
        }
        __syncthreads();
    }

    // FC: out[t][cls] = b_fc[cls] + hs[t] . W_fc[cls]
    if (tid < NG * 10) {
        int t = tid / 10, cls = tid - t * 10;
        const float4* hv4 = (const float4*)(hs + t * DIM);
        const float4* wf4 = (const float4*)(Wfc + cls * DIM);
        float acc = bfc[cls];
#pragma unroll
        for (int kk = 0; kk < 32; ++kk) {
            float4 h = hv4[kk];
            float4 w = wf4[kk];
            acc += h.x * w.x + h.y * w.y + h.z * w.z + h.w * w.w;
        }
        out[tid] = acc;
    }
}

extern "C" void kernel_launch(void* const* d_in, const int* in_sizes, int n_in,
                              void* d_out, int out_size, void* d_ws, size_t ws_size,
                              hipStream_t stream) {
    const float* x     = (const float*)d_in[0];
    const int*   ei    = (const int*)d_in[1];
    const int*   batch = (const int*)d_in[2];
    const float* W_gcn = (const float*)d_in[3];
    const float* b_gcn = (const float*)d_in[4];
    const float* w_ih  = (const float*)d_in[5];
    const float* w_hh  = (const float*)d_in[6];
    const float* b_ih  = (const float*)d_in[7];
    const float* b_hh  = (const float*)d_in[8];
    const float* W_fc  = (const float*)d_in[9];
    const float* b_fc  = (const float*)d_in[10];
    float* out = (float*)d_out;

    float* ws    = (float*)d_ws;
    float* y     = ws;                               // 12.8M floats
    float* agg2  = y + (size_t)NNODES * DIM;         // 12.8M floats
    float* dinv  = agg2 + (size_t)NNODES * DIM;      // 100096
    float* deg   = dinv + 100096;                    // 100096
    float* sums  = deg + 100096;                     // 8192
    float* xg    = sums + NG * DIM;                  // 32768
    int*   start = (int*)(xg + NG * GATE);           // 65

    hipMemsetAsync(deg, 0, NNODES * sizeof(float), stream);
    hipMemsetAsync(sums, 0, NG * DIM * sizeof(float), stream);

    k_deg<<<(NEDGES + 255) / 256, 256, 0, stream>>>(ei, deg);
    k_dinv<<<(NNODES + 255) / 256, 256, 0, stream>>>(deg, dinv);
    k_gemm<<<(NNODES + 63) / 64, 256, 0, stream>>>(x, W_gcn, dinv, y, agg2);
    k_scatter<<<(NEDGES + 31) / 32, 256, 0, stream>>>(ei, (const float4*)y, agg2);
    k_bounds<<<1, 128, 0, stream>>>(batch, start);
    k_pool<<<NG * CH, 128, 0, stream>>>(agg2, dinv, b_gcn, start, sums);
    k_xgate<<<NG, 512, 0, stream>>>(sums, start, w_ih, b_ih, b_hh, xg);
    k_lstm<<<1, 1024, 0, stream>>>(xg, w_hh, W_fc, b_fc, out);
}

// Round 2
// 674.007 us; speedup vs baseline: 4.4399x; 4.4399x over previous
//
#include <hip/hip_runtime.h>
#include <math.h>

#define NNODES 100000
#define NEDGES 1600000
#define DIM 128
#define NG 64
#define GATE 512
#define CH 16

__device__ __forceinline__ float sigf(float x) { return 1.0f / (1.0f + __expf(-x)); }
__device__ __forceinline__ float tanhfast(float x) {
    float e = __expf(2.0f * x);
    return 1.0f - 2.0f / (e + 1.0f);
}

// in-degree count by col (int atomics)
__global__ __launch_bounds__(256) void k_deg(const int* __restrict__ ei, int* __restrict__ deg) {
    int e = blockIdx.x * 256 + threadIdx.x;
    if (e < NEDGES) atomicAdd(&deg[ei[NEDGES + e]], 1);
}

// exclusive scan of deg -> row_ptr (single block, 1024 threads)
__global__ __launch_bounds__(1024) void k_scan(const int* __restrict__ deg, int* __restrict__ row_ptr) {
    __shared__ int ls[1024];
    int tid = threadIdx.x;
    const int CHUNK = (NNODES + 1023) / 1024;  // 98
    int n0 = tid * CHUNK;
    int n1 = n0 + CHUNK; if (n1 > NNODES) n1 = NNODES;
    int s = 0;
    for (int n = n0; n < n1; ++n) s += deg[n];
    ls[tid] = s;
    __syncthreads();
    for (int off = 1; off < 1024; off <<= 1) {
        int v = (tid >= off) ? ls[tid - off] : 0;
        __syncthreads();
        ls[tid] += v;
        __syncthreads();
    }
    int base = (tid == 0) ? 0 : ls[tid - 1];
    for (int n = n0; n < n1; ++n) { row_ptr[n] = base; base += deg[n]; }
    if (tid == 1023) row_ptr[NNODES] = base;
}

__global__ __launch_bounds__(256) void k_dinv(const int* __restrict__ deg, float* __restrict__ dinv) {
    int n = blockIdx.x * 256 + threadIdx.x;
    if (n < NNODES) dinv[n] = rsqrtf((float)deg[n] + 1.0f);
}

// adj[row_ptr[col] + cursor[col]++] = row
__global__ __launch_bounds__(256) void k_fill(const int* __restrict__ ei, const int* __restrict__ row_ptr,
                                              int* __restrict__ cursor, int* __restrict__ adj) {
    int e = blockIdx.x * 256 + threadIdx.x;
    if (e < NEDGES) {
        int row = ei[e];
        int col = ei[NEDGES + e];
        int pos = atomicAdd(&cursor[col], 1);
        adj[row_ptr[col] + pos] = row;
    }
}

// y[n] = (x[n] @ W) * dinv[n]
__global__ __launch_bounds__(256) void k_gemm(const float* __restrict__ x, const float* __restrict__ W,
                                              const float* __restrict__ dinv, float* __restrict__ y) {
    __shared__ float4 Wl[DIM * DIM / 4];  // 64 KB
    const float4* W4 = (const float4*)W;
    int tid = threadIdx.x;
#pragma unroll
    for (int l = 0; l < 16; ++l) Wl[tid + l * 256] = W4[tid + l * 256];
    __syncthreads();

    int tr = tid >> 5, tc = tid & 31;
    int rb = blockIdx.x * 64;
    const float4* x4 = (const float4*)x;

    int r[8];
    bool valid[8];
#pragma unroll
    for (int i = 0; i < 8; ++i) {
        int rr = rb + tr * 8 + i;
        valid[i] = rr < NNODES;
        r[i] = valid[i] ? rr : (NNODES - 1);
    }

    float4 acc[8];
#pragma unroll
    for (int i = 0; i < 8; ++i) acc[i] = make_float4(0.f, 0.f, 0.f, 0.f);

    for (int k = 0; k < DIM; k += 4) {
        float4 wv[4];
#pragma unroll
        for (int kk = 0; kk < 4; ++kk) wv[kk] = Wl[(k + kk) * 32 + tc];
#pragma unroll
        for (int i = 0; i < 8; ++i) {
            float4 xv = x4[(size_t)r[i] * 32 + (k >> 2)];
            acc[i].x += xv.x * wv[0].x + xv.y * wv[1].x + xv.z * wv[2].x + xv.w * wv[3].x;
            acc[i].y += xv.x * wv[0].y + xv.y * wv[1].y + xv.z * wv[2].y + xv.w * wv[3].y;
            acc[i].z += xv.x * wv[0].z + xv.y * wv[1].z + xv.z * wv[2].z + xv.w * wv[3].z;
            acc[i].w += xv.x * wv[0].w + xv.y * wv[1].w + xv.z * wv[2].w + xv.w * wv[3].w;
        }
    }

    float4* y4 = (float4*)y;
#pragma unroll
    for (int i = 0; i < 8; ++i) {
        if (valid[i]) {
            float dv = dinv[r[i]];
            y4[(size_t)r[i] * 32 + tc] = make_float4(acc[i].x * dv, acc[i].y * dv, acc[i].z * dv, acc[i].w * dv);
        }
    }
}

// agg2[n] = y[n] + sum over in-neighbors y[row]  (CSR gather, no atomics)
__global__ __launch_bounds__(256) void k_gather(const int* __restrict__ row_ptr, const int* __restrict__ adj,
                                                const float4* __restrict__ y4, float4* __restrict__ agg2) {
    int grp = threadIdx.x >> 5;  // 8 nodes per block
    int l = threadIdx.x & 31;    // 32 lanes x float4 = 128 dims
    int n = blockIdx.x * 8 + grp;
    if (n >= NNODES) return;
    int s = row_ptr[n], e = row_ptr[n + 1];
    float4 a0 = y4[(size_t)n * 32 + l];  // self-loop term
    float4 a1 = make_float4(0.f, 0.f, 0.f, 0.f);
    int i = s;
    for (; i + 1 < e; i += 2) {
        int r0 = adj[i], r1 = adj[i + 1];
        float4 v0 = y4[(size_t)r0 * 32 + l];
        float4 v1 = y4[(size_t)r1 * 32 + l];
        a0.x += v0.x; a0.y += v0.y; a0.z += v0.z; a0.w += v0.w;
        a1.x += v1.x; a1.y += v1.y; a1.z += v1.z; a1.w += v1.w;
    }
    if (i < e) {
        int r0 = adj[i];
        float4 v0 = y4[(size_t)r0 * 32 + l];
        a0.x += v0.x; a0.y += v0.y; a0.z += v0.z; a0.w += v0.w;
    }
    agg2[(size_t)n * 32 + l] = make_float4(a0.x + a1.x, a0.y + a1.y, a0.z + a1.z, a0.w + a1.w);
}

// graph segment boundaries (batch is sorted)
__global__ void k_bounds(const int* __restrict__ batch, int* __restrict__ start) {
    int g = threadIdx.x;
    if (g <= NG) {
        int lo = 0, hi = NNODES;
        while (lo < hi) {
            int mid = (lo + hi) >> 1;
            if (batch[mid] < g) lo = mid + 1; else hi = mid;
        }
        start[g] = lo;
    }
}

// sums[g][d] = sum over nodes of relu(dinv[n]*agg2[n][d] + b[d])
__global__ __launch_bounds__(128) void k_pool(const float* __restrict__ agg2, const float* __restrict__ dinv,
                                              const float* __restrict__ b, const int* __restrict__ start,
                                              float* __restrict__ sums) {
    int g = blockIdx.x / CH, q = blockIdx.x % CH;
    int d = threadIdx.x;
    int s = start[g], e = start[g + 1];
    int len = e - s;
    int n0 = s + (int)((long)len * q / CH);
    int n1 = s + (int)((long)len * (q + 1) / CH);
    float bias = b[d];
    float acc = 0.f;
    for (int n = n0; n < n1; ++n) {
        float v = dinv[n] * agg2[(size_t)n * DIM + d] + bias;
        acc += fmaxf(v, 0.f);
    }
    atomicAdd(&sums[g * DIM + d], acc);
}

// xg[t][j] = b_ih[j] + b_hh[j] + pooled[t] . w_ih[j]
__global__ __launch_bounds__(512) void k_xgate(const float* __restrict__ sums, const int* __restrict__ start,
                                               const float* __restrict__ w_ih, const float* __restrict__ b_ih,
                                               const float* __restrict__ b_hh, float* __restrict__ xg) {
    __shared__ float4 p4[DIM / 4];
    int t = blockIdx.x, j = threadIdx.x;
    if (j < DIM) {
        int c = start[t + 1] - start[t];
        float inv = 1.0f / fmaxf((float)c, 1.0f);
        ((float*)p4)[j] = sums[t * DIM + j] * inv;
    }
    __syncthreads();
    const float4* w4 = (const float4*)(w_ih + (size_t)j * DIM);
    float acc = b_ih[j] + b_hh[j];
#pragma unroll
    for (int kk = 0; kk < 32; ++kk) {
        float4 w = w4[kk];
        float4 p = p4[kk];
        acc += w.x * p.x + w.y * p.y + w.z * p.z + w.w * p.w;
    }
    xg[t * GATE + j] = acc;
}

// sequential LSTM recurrence + final FC, single block
__global__ __launch_bounds__(1024) void k_lstm(const float* __restrict__ xg, const float* __restrict__ w_hh,
                                               const float* __restrict__ Wfc, const float* __restrict__ bfc,
                                               float* __restrict__ out) {
    __shared__ float h_lds[DIM];
    __shared__ float gates[GATE];
    __shared__ float hs[NG * DIM];  // 32 KB
    int tid = threadIdx.x;
    int j = tid >> 1, half = tid & 1;

    float4 wv[16];
    const float4* w4 = (const float4*)(w_hh + (size_t)j * DIM + half * 64);
#pragma unroll
    for (int kk = 0; kk < 16; ++kk) wv[kk] = w4[kk];

    float c = 0.f;
    if (tid < DIM) h_lds[tid] = 0.f;
    __syncthreads();

    const float4* h4 = (const float4*)h_lds;
    for (int t = 0; t < NG; ++t) {
        float acc = (half == 0) ? xg[t * GATE + j] : 0.f;
#pragma unroll
        for (int kk = 0; kk < 16; ++kk) {
            float4 hv = h4[half * 16 + kk];
            float4 w = wv[kk];
            acc += w.x * hv.x + w.y * hv.y + w.z * hv.z + w.w * hv.w;
        }
        acc += __shfl_xor(acc, 1, 64);
        if (half == 0) gates[j] = acc;
        __syncthreads();
        if (tid < DIM) {
            float gi = gates[tid], gf = gates[DIM + tid], gg = gates[2 * DIM + tid], go = gates[3 * DIM + tid];
            c = sigf(gf) * c + sigf(gi) * tanhfast(gg);
            float hn = sigf(go) * tanhfast(c);
            h_lds[tid] = hn;
            hs[t * DIM + tid] = hn;
        }
        __syncthreads();
    }

    if (tid < NG * 10) {
        int t = tid / 10, cls = tid - t * 10;
        const float4* hv4 = (const float4*)(hs + t * DIM);
        const float4* wf4 = (const float4*)(Wfc + cls * DIM);
        float acc = bfc[cls];
#pragma unroll
        for (int kk = 0; kk < 32; ++kk) {
            float4 h = hv4[kk];
            float4 w = wf4[kk];
            acc += h.x * w.x + h.y * w.y + h.z * w.z + h.w * w.w;
        }
        out[tid] = acc;
    }
}

extern "C" void kernel_launch(void* const* d_in, const int* in_sizes, int n_in,
                              void* d_out, int out_size, void* d_ws, size_t ws_size,
                              hipStream_t stream) {
    const float* x     = (const float*)d_in[0];
    const int*   ei    = (const int*)d_in[1];
    const int*   batch = (const int*)d_in[2];
    const float* W_gcn = (const float*)d_in[3];
    const float* b_gcn = (const float*)d_in[4];
    const float* w_ih  = (const float*)d_in[5];
    const float* w_hh  = (const float*)d_in[6];
    const float* b_ih  = (const float*)d_in[7];
    const float* b_hh  = (const float*)d_in[8];
    const float* W_fc  = (const float*)d_in[9];
    const float* b_fc  = (const float*)d_in[10];
    float* out = (float*)d_out;

    float* ws      = (float*)d_ws;
    float* y       = ws;                               // 12.8M floats
    float* agg2    = y + (size_t)NNODES * DIM;         // 12.8M floats
    float* dinv    = agg2 + (size_t)NNODES * DIM;      // 100096
    float* sums    = dinv + 100096;                    // 8192
    float* xg      = sums + NG * DIM;                  // 32768
    int*   deg     = (int*)(xg + NG * GATE);           // 100096
    int*   row_ptr = deg + 100096;                     // 100096 (needs 100001)
    int*   cursor  = row_ptr + 100096;                 // 100096
    int*   adj     = cursor + 100096;                  // 1.6M
    int*   start   = adj + NEDGES;                     // 65

    hipMemsetAsync(deg, 0, NNODES * sizeof(int), stream);
    hipMemsetAsync(cursor, 0, NNODES * sizeof(int), stream);
    hipMemsetAsync(sums, 0, NG * DIM * sizeof(float), stream);

    k_deg<<<(NEDGES + 255) / 256, 256, 0, stream>>>(ei, deg);
    k_scan<<<1, 1024, 0, stream>>>(deg, row_ptr);
    k_dinv<<<(NNODES + 255) / 256, 256, 0, stream>>>(deg, dinv);
    k_fill<<<(NEDGES + 255) / 256, 256, 0, stream>>>(ei, row_ptr, cursor, adj);
    k_gemm<<<(NNODES + 63) / 64, 256, 0, stream>>>(x, W_gcn, dinv, y);
    k_gather<<<(NNODES + 7) / 8, 256, 0, stream>>>(row_ptr, adj, (const float4*)y, (float4*)agg2);
    k_bounds<<<1, 128, 0, stream>>>(batch, start);
    k_pool<<<NG * CH, 128, 0, stream>>>(agg2, dinv, b_gcn, start, sums);
    k_xgate<<<NG, 512, 0, stream>>>(sums, start, w_ih, b_ih, b_hh, xg);
    k_lstm<<<1, 1024, 0, stream>>>(xg, w_hh, W_fc, b_fc, out);
}

// Round 3
// 519.171 us; speedup vs baseline: 5.7640x; 1.2982x over previous
//
#include <hip/hip_runtime.h>
#include <math.h>

#define NNODES 100000
#define NEDGES 1600000
#define DIM 128
#define NG 64
#define GATE 512
#define CH 16
#define SCAN_NB 98  // ceil(NNODES / 1024)

__device__ __forceinline__ float sigf(float x) { return 1.0f / (1.0f + __expf(-x)); }
__device__ __forceinline__ float tanhfast(float x) {
    float e = __expf(2.0f * x);
    return 1.0f - 2.0f / (e + 1.0f);
}

// in-degree count by col (int atomics)
__global__ __launch_bounds__(256) void k_deg(const int* __restrict__ ei, int* __restrict__ deg) {
    int e = blockIdx.x * 256 + threadIdx.x;
    if (e < NEDGES) atomicAdd(&deg[ei[NEDGES + e]], 1);
}

// stage 1: per-block exclusive scan of deg; block sums out
__global__ __launch_bounds__(1024) void k_scan1(const int* __restrict__ deg, int* __restrict__ row_ptr,
                                                int* __restrict__ bsum) {
    __shared__ int ls[1024];
    int tid = threadIdx.x;
    int n = blockIdx.x * 1024 + tid;
    int v = (n < NNODES) ? deg[n] : 0;
    ls[tid] = v;
    __syncthreads();
    for (int off = 1; off < 1024; off <<= 1) {
        int t = (tid >= off) ? ls[tid - off] : 0;
        __syncthreads();
        ls[tid] += t;
        __syncthreads();
    }
    if (n < NNODES) row_ptr[n] = ls[tid] - v;  // exclusive within block
    if (tid == 1023) bsum[blockIdx.x] = ls[1023];
}

// stage 2: exclusive scan of the block sums (single tiny block)
__global__ __launch_bounds__(128) void k_scan2(int* __restrict__ bsum, int* __restrict__ row_ptr) {
    __shared__ int ls[128];
    int tid = threadIdx.x;
    int v = (tid < SCAN_NB) ? bsum[tid] : 0;
    ls[tid] = v;
    __syncthreads();
    for (int off = 1; off < 128; off <<= 1) {
        int t = (tid >= off) ? ls[tid - off] : 0;
        __syncthreads();
        ls[tid] += t;
        __syncthreads();
    }
    if (tid < SCAN_NB) bsum[tid] = ls[tid] - v;  // exclusive block offsets
    if (tid == 127) row_ptr[NNODES] = ls[127];
}

// stage 3: add block offsets; also compute dinv
__global__ __launch_bounds__(1024) void k_scan3(const int* __restrict__ deg, int* __restrict__ row_ptr,
                                                const int* __restrict__ bsum, float* __restrict__ dinv) {
    int n = blockIdx.x * 1024 + threadIdx.x;
    if (n < NNODES) {
        row_ptr[n] += bsum[blockIdx.x];
        dinv[n] = rsqrtf((float)deg[n] + 1.0f);
    }
}

// adj[row_ptr[col] + cursor[col]++] = row
__global__ __launch_bounds__(256) void k_fill(const int* __restrict__ ei, const int* __restrict__ row_ptr,
                                              int* __restrict__ cursor, int* __restrict__ adj) {
    int e = blockIdx.x * 256 + threadIdx.x;
    if (e < NEDGES) {
        int row = ei[e];
        int col = ei[NEDGES + e];
        int pos = atomicAdd(&cursor[col], 1);
        adj[row_ptr[col] + pos] = row;
    }
}

// y[n] = (x[n] @ W) * dinv[n]
__global__ __launch_bounds__(256) void k_gemm(const float* __restrict__ x, const float* __restrict__ W,
                                              const float* __restrict__ dinv, float* __restrict__ y) {
    __shared__ float4 Wl[DIM * DIM / 4];  // 64 KB
    const float4* W4 = (const float4*)W;
    int tid = threadIdx.x;
#pragma unroll
    for (int l = 0; l < 16; ++l) Wl[tid + l * 256] = W4[tid + l * 256];
    __syncthreads();

    int tr = tid >> 5, tc = tid & 31;
    int rb = blockIdx.x * 64;
    const float4* x4 = (const float4*)x;

    int r[8];
    bool valid[8];
#pragma unroll
    for (int i = 0; i < 8; ++i) {
        int rr = rb + tr * 8 + i;
        valid[i] = rr < NNODES;
        r[i] = valid[i] ? rr : (NNODES - 1);
    }

    float4 acc[8];
#pragma unroll
    for (int i = 0; i < 8; ++i) acc[i] = make_float4(0.f, 0.f, 0.f, 0.f);

    for (int k = 0; k < DIM; k += 4) {
        float4 wv[4];
#pragma unroll
        for (int kk = 0; kk < 4; ++kk) wv[kk] = Wl[(k + kk) * 32 + tc];
#pragma unroll
        for (int i = 0; i < 8; ++i) {
            float4 xv = x4[(size_t)r[i] * 32 + (k >> 2)];
            acc[i].x += xv.x * wv[0].x + xv.y * wv[1].x + xv.z * wv[2].x + xv.w * wv[3].x;
            acc[i].y += xv.x * wv[0].y + xv.y * wv[1].y + xv.z * wv[2].y + xv.w * wv[3].y;
            acc[i].z += xv.x * wv[0].z + xv.y * wv[1].z + xv.z * wv[2].z + xv.w * wv[3].z;
            acc[i].w += xv.x * wv[0].w + xv.y * wv[1].w + xv.z * wv[2].w + xv.w * wv[3].w;
        }
    }

    float4* y4 = (float4*)y;
#pragma unroll
    for (int i = 0; i < 8; ++i) {
        if (valid[i]) {
            float dv = dinv[r[i]];
            y4[(size_t)r[i] * 32 + tc] = make_float4(acc[i].x * dv, acc[i].y * dv, acc[i].z * dv, acc[i].w * dv);
        }
    }
}

// agg2[n] = y[n] + sum over in-neighbors y[row]  (CSR gather, no atomics)
__global__ __launch_bounds__(256) void k_gather(const int* __restrict__ row_ptr, const int* __restrict__ adj,
                                                const float4* __restrict__ y4, float4* __restrict__ agg2) {
    int grp = threadIdx.x >> 5;  // 8 nodes per block
    int l = threadIdx.x & 31;    // 32 lanes x float4 = 128 dims
    int n = blockIdx.x * 8 + grp;
    if (n >= NNODES) return;
    int s = row_ptr[n], e = row_ptr[n + 1];
    float4 a0 = y4[(size_t)n * 32 + l];  // self-loop term
    float4 a1 = make_float4(0.f, 0.f, 0.f, 0.f);
    int i = s;
    for (; i + 1 < e; i += 2) {
        int r0 = adj[i], r1 = adj[i + 1];
        float4 v0 = y4[(size_t)r0 * 32 + l];
        float4 v1 = y4[(size_t)r1 * 32 + l];
        a0.x += v0.x; a0.y += v0.y; a0.z += v0.z; a0.w += v0.w;
        a1.x += v1.x; a1.y += v1.y; a1.z += v1.z; a1.w += v1.w;
    }
    if (i < e) {
        int r0 = adj[i];
        float4 v0 = y4[(size_t)r0 * 32 + l];
        a0.x += v0.x; a0.y += v0.y; a0.z += v0.z; a0.w += v0.w;
    }
    agg2[(size_t)n * 32 + l] = make_float4(a0.x + a1.x, a0.y + a1.y, a0.z + a1.z, a0.w + a1.w);
}

// graph segment boundaries (batch is sorted)
__global__ void k_bounds(const int* __restrict__ batch, int* __restrict__ start) {
    int g = threadIdx.x;
    if (g <= NG) {
        int lo = 0, hi = NNODES;
        while (lo < hi) {
            int mid = (lo + hi) >> 1;
            if (batch[mid] < g) lo = mid + 1; else hi = mid;
        }
        start[g] = lo;
    }
}

// sums[g][d] = sum over nodes of relu(dinv[n]*agg2[n][d] + b[d])
__global__ __launch_bounds__(128) void k_pool(const float* __restrict__ agg2, const float* __restrict__ dinv,
                                              const float* __restrict__ b, const int* __restrict__ start,
                                              float* __restrict__ sums) {
    int g = blockIdx.x / CH, q = blockIdx.x % CH;
    int d = threadIdx.x;
    int s = start[g], e = start[g + 1];
    int len = e - s;
    int n0 = s + (int)((long)len * q / CH);
    int n1 = s + (int)((long)len * (q + 1) / CH);
    float bias = b[d];
    float acc = 0.f;
    for (int n = n0; n < n1; ++n) {
        float v = dinv[n] * agg2[(size_t)n * DIM + d] + bias;
        acc += fmaxf(v, 0.f);
    }
    atomicAdd(&sums[g * DIM + d], acc);
}

// xg[t][j] = b_ih[j] + b_hh[j] + pooled[t] . w_ih[j]
__global__ __launch_bounds__(512) void k_xgate(const float* __restrict__ sums, const int* __restrict__ start,
                                               const float* __restrict__ w_ih, const float* __restrict__ b_ih,
                                               const float* __restrict__ b_hh, float* __restrict__ xg) {
    __shared__ float4 p4[DIM / 4];
    int t = blockIdx.x, j = threadIdx.x;
    if (j < DIM) {
        int c = start[t + 1] - start[t];
        float inv = 1.0f / fmaxf((float)c, 1.0f);
        ((float*)p4)[j] = sums[t * DIM + j] * inv;
    }
    __syncthreads();
    const float4* w4 = (const float4*)(w_ih + (size_t)j * DIM);
    float acc = b_ih[j] + b_hh[j];
#pragma unroll
    for (int kk = 0; kk < 32; ++kk) {
        float4 w = w4[kk];
        float4 p = p4[kk];
        acc += w.x * p.x + w.y * p.y + w.z * p.z + w.w * p.w;
    }
    xg[t * GATE + j] = acc;
}

// sequential LSTM recurrence + final FC, single block
__global__ __launch_bounds__(1024) void k_lstm(const float* __restrict__ xg, const float* __restrict__ w_hh,
                                               const float* __restrict__ Wfc, const float* __restrict__ bfc,
                                               float* __restrict__ out) {
    __shared__ float h_lds[DIM];
    __shared__ float gates[GATE];
    __shared__ float hs[NG * DIM];  // 32 KB
    int tid = threadIdx.x;
    int j = tid >> 1, half = tid & 1;

    float4 wv[16];
    const float4* w4 = (const float4*)(w_hh + (size_t)j * DIM + half * 64);
#pragma unroll
    for (int kk = 0; kk < 16; ++kk) wv[kk] = w4[kk];

    float c = 0.f;
    if (tid < DIM) h_lds[tid] = 0.f;
    __syncthreads();

    const float4* h4 = (const float4*)h_lds;
    for (int t = 0; t < NG; ++t) {
        float acc = (half == 0) ? xg[t * GATE + j] : 0.f;
#pragma unroll
        for (int kk = 0; kk < 16; ++kk) {
            float4 hv = h4[half * 16 + kk];
            float4 w = wv[kk];
            acc += w.x * hv.x + w.y * hv.y + w.z * hv.z + w.w * hv.w;
        }
        acc += __shfl_xor(acc, 1, 64);
        if (half == 0) gates[j] = acc;
        __syncthreads();
        if (tid < DIM) {
            float gi = gates[tid], gf = gates[DIM + tid], gg = gates[2 * DIM + tid], go = gates[3 * DIM + tid];
            c = sigf(gf) * c + sigf(gi) * tanhfast(gg);
            float hn = sigf(go) * tanhfast(c);
            h_lds[tid] = hn;
            hs[t * DIM + tid] = hn;
        }
        __syncthreads();
    }

    if (tid < NG * 10) {
        int t = tid / 10, cls = tid - t * 10;
        const float4* hv4 = (const float4*)(hs + t * DIM);
        const float4* wf4 = (const float4*)(Wfc + cls * DIM);
        float acc = bfc[cls];
#pragma unroll
        for (int kk = 0; kk < 32; ++kk) {
            float4 h = hv4[kk];
            float4 w = wf4[kk];
            acc += h.x * w.x + h.y * w.y + h.z * w.z + h.w * w.w;
        }
        out[tid] = acc;
    }
}

extern "C" void kernel_launch(void* const* d_in, const int* in_sizes, int n_in,
                              void* d_out, int out_size, void* d_ws, size_t ws_size,
                              hipStream_t stream) {
    const float* x     = (const float*)d_in[0];
    const int*   ei    = (const int*)d_in[1];
    const int*   batch = (const int*)d_in[2];
    const float* W_gcn = (const float*)d_in[3];
    const float* b_gcn = (const float*)d_in[4];
    const float* w_ih  = (const float*)d_in[5];
    const float* w_hh  = (const float*)d_in[6];
    const float* b_ih  = (const float*)d_in[7];
    const float* b_hh  = (const float*)d_in[8];
    const float* W_fc  = (const float*)d_in[9];
    const float* b_fc  = (const float*)d_in[10];
    float* out = (float*)d_out;

    float* ws      = (float*)d_ws;
    float* y       = ws;                               // 12.8M floats
    float* agg2    = y + (size_t)NNODES * DIM;         // 12.8M floats
    float* dinv    = agg2 + (size_t)NNODES * DIM;      // 100096
    float* sums    = dinv + 100096;                    // 8192
    float* xg      = sums + NG * DIM;                  // 32768
    int*   deg     = (int*)(xg + NG * GATE);           // 100096
    int*   row_ptr = deg + 100096;                     // 100096 (needs 100001)
    int*   cursor  = row_ptr + 100096;                 // 100096
    int*   adj     = cursor + 100096;                  // 1.6M
    int*   start   = adj + NEDGES;                     // 128
    int*   bsum    = start + 128;                      // 128

    hipMemsetAsync(deg, 0, NNODES * sizeof(int), stream);
    hipMemsetAsync(cursor, 0, NNODES * sizeof(int), stream);
    hipMemsetAsync(sums, 0, NG * DIM * sizeof(float), stream);

    k_deg<<<(NEDGES + 255) / 256, 256, 0, stream>>>(ei, deg);
    k_scan1<<<SCAN_NB, 1024, 0, stream>>>(deg, row_ptr, bsum);
    k_scan2<<<1, 128, 0, stream>>>(bsum, row_ptr);
    k_scan3<<<SCAN_NB, 1024, 0, stream>>>(deg, row_ptr, bsum, dinv);
    k_fill<<<(NEDGES + 255) / 256, 256, 0, stream>>>(ei, row_ptr, cursor, adj);
    k_gemm<<<(NNODES + 63) / 64, 256, 0, stream>>>(x, W_gcn, dinv, y);
    k_gather<<<(NNODES + 7) / 8, 256, 0, stream>>>(row_ptr, adj, (const float4*)y, (float4*)agg2);
    k_bounds<<<1, 128, 0, stream>>>(batch, start);
    k_pool<<<NG * CH, 128, 0, stream>>>(agg2, dinv, b_gcn, start, sums);
    k_xgate<<<NG, 512, 0, stream>>>(sums, start, w_ih, b_ih, b_hh, xg);
    k_lstm<<<1, 1024, 0, stream>>>(xg, w_hh, W_fc, b_fc, out);
}

// Round 4
// 505.912 us; speedup vs baseline: 5.9151x; 1.0262x over previous
//
#include <hip/hip_runtime.h>
#include <hip/hip_fp16.h>
#include <math.h>

#define NNODES 100000
#define NEDGES 1600000
#define DIM 128
#define NG 64
#define GATE 512
#define CH 16
#define SCAN_NB 98  // ceil(NNODES / 1024)

struct alignas(8) half4v { __half2 a, b; };

__device__ __forceinline__ float sigf(float x) { return 1.0f / (1.0f + __expf(-x)); }
__device__ __forceinline__ float tanhfast(float x) {
    float e = __expf(2.0f * x);
    return 1.0f - 2.0f / (e + 1.0f);
}
__device__ __forceinline__ float4 h4tof4(half4v v) {
    float2 p = __half22float2(v.a);
    float2 q = __half22float2(v.b);
    return make_float4(p.x, p.y, q.x, q.y);
}

// in-degree count by col (int atomics)
__global__ __launch_bounds__(256) void k_deg(const int* __restrict__ ei, int* __restrict__ deg) {
    int e = blockIdx.x * 256 + threadIdx.x;
    if (e < NEDGES) atomicAdd(&deg[ei[NEDGES + e]], 1);
}

// stage 1: per-block exclusive scan of deg; block sums out
__global__ __launch_bounds__(1024) void k_scan1(const int* __restrict__ deg, int* __restrict__ row_ptr,
                                                int* __restrict__ bsum) {
    __shared__ int ls[1024];
    int tid = threadIdx.x;
    int n = blockIdx.x * 1024 + tid;
    int v = (n < NNODES) ? deg[n] : 0;
    ls[tid] = v;
    __syncthreads();
    for (int off = 1; off < 1024; off <<= 1) {
        int t = (tid >= off) ? ls[tid - off] : 0;
        __syncthreads();
        ls[tid] += t;
        __syncthreads();
    }
    if (n < NNODES) row_ptr[n] = ls[tid] - v;  // exclusive within block
    if (tid == 1023) bsum[blockIdx.x] = ls[1023];
}

// stage 2: exclusive scan of block sums + graph segment bounds (batch sorted)
__global__ __launch_bounds__(128) void k_scan2(int* __restrict__ bsum, int* __restrict__ row_ptr,
                                               const int* __restrict__ batch, int* __restrict__ start) {
    __shared__ int ls[128];
    int tid = threadIdx.x;
    int v = (tid < SCAN_NB) ? bsum[tid] : 0;
    ls[tid] = v;
    __syncthreads();
    for (int off = 1; off < 128; off <<= 1) {
        int t = (tid >= off) ? ls[tid - off] : 0;
        __syncthreads();
        ls[tid] += t;
        __syncthreads();
    }
    if (tid < SCAN_NB) bsum[tid] = ls[tid] - v;  // exclusive block offsets
    if (tid == 127) row_ptr[NNODES] = ls[127];
    // graph bounds via binary search
    if (tid <= NG) {
        int lo = 0, hi = NNODES;
        while (lo < hi) {
            int mid = (lo + hi) >> 1;
            if (batch[mid] < tid) lo = mid + 1; else hi = mid;
        }
        start[tid] = lo;
    }
}

// stage 3: add block offsets; init cursor = row_ptr; compute dinv
__global__ __launch_bounds__(1024) void k_scan3(const int* __restrict__ deg, int* __restrict__ row_ptr,
                                                const int* __restrict__ bsum, int* __restrict__ cursor,
                                                float* __restrict__ dinv) {
    int n = blockIdx.x * 1024 + threadIdx.x;
    if (n < NNODES) {
        int rp = row_ptr[n] + bsum[blockIdx.x];
        row_ptr[n] = rp;
        cursor[n] = rp;
        dinv[n] = rsqrtf((float)deg[n] + 1.0f);
    }
}

// adj[cursor[col]++] = row  (cursor pre-seeded with row_ptr)
__global__ __launch_bounds__(256) void k_fill(const int* __restrict__ ei, int* __restrict__ cursor,
                                              int* __restrict__ adj) {
    int e = blockIdx.x * 256 + threadIdx.x;
    if (e < NEDGES) {
        int row = ei[e];
        int col = ei[NEDGES + e];
        int pos = atomicAdd(&cursor[col], 1);
        adj[pos] = row;
    }
}

// y[n] = (x[n] @ W) * dinv[n], stored fp16
__global__ __launch_bounds__(256) void k_gemm(const float* __restrict__ x, const float* __restrict__ W,
                                              const float* __restrict__ dinv, half4v* __restrict__ yh) {
    __shared__ float4 Wl[DIM * DIM / 4];  // 64 KB
    const float4* W4 = (const float4*)W;
    int tid = threadIdx.x;
#pragma unroll
    for (int l = 0; l < 16; ++l) Wl[tid + l * 256] = W4[tid + l * 256];
    __syncthreads();

    int tr = tid >> 5, tc = tid & 31;
    int rb = blockIdx.x * 64;
    const float4* x4 = (const float4*)x;

    int r[8];
    bool valid[8];
#pragma unroll
    for (int i = 0; i < 8; ++i) {
        int rr = rb + tr * 8 + i;
        valid[i] = rr < NNODES;
        r[i] = valid[i] ? rr : (NNODES - 1);
    }

    float4 acc[8];
#pragma unroll
    for (int i = 0; i < 8; ++i) acc[i] = make_float4(0.f, 0.f, 0.f, 0.f);

    for (int k = 0; k < DIM; k += 4) {
        float4 wv[4];
#pragma unroll
        for (int kk = 0; kk < 4; ++kk) wv[kk] = Wl[(k + kk) * 32 + tc];
#pragma unroll
        for (int i = 0; i < 8; ++i) {
            float4 xv = x4[(size_t)r[i] * 32 + (k >> 2)];
            acc[i].x += xv.x * wv[0].x + xv.y * wv[1].x + xv.z * wv[2].x + xv.w * wv[3].x;
            acc[i].y += xv.x * wv[0].y + xv.y * wv[1].y + xv.z * wv[2].y + xv.w * wv[3].y;
            acc[i].z += xv.x * wv[0].z + xv.y * wv[1].z + xv.z * wv[2].z + xv.w * wv[3].z;
            acc[i].w += xv.x * wv[0].w + xv.y * wv[1].w + xv.z * wv[2].w + xv.w * wv[3].w;
        }
    }

#pragma unroll
    for (int i = 0; i < 8; ++i) {
        if (valid[i]) {
            float dv = dinv[r[i]];
            half4v v;
            v.a = __floats2half2_rn(acc[i].x * dv, acc[i].y * dv);
            v.b = __floats2half2_rn(acc[i].z * dv, acc[i].w * dv);
            yh[(size_t)r[i] * 32 + tc] = v;
        }
    }
}

// agg2[n] = y[n] + sum over in-neighbors y[row]  (CSR gather, fp16 in/out, f32 accum)
__global__ __launch_bounds__(256) void k_gather(const int* __restrict__ row_ptr, const int* __restrict__ adj,
                                                const half4v* __restrict__ yh, half4v* __restrict__ agg2) {
    int grp = threadIdx.x >> 5;  // 8 nodes per block
    int l = threadIdx.x & 31;    // 32 lanes x 4 dims = 128 dims
    int n = blockIdx.x * 8 + grp;
    if (n >= NNODES) return;
    int s = row_ptr[n], e = row_ptr[n + 1];
    float4 a0 = h4tof4(yh[(size_t)n * 32 + l]);  // self-loop term
    float4 a1 = make_float4(0.f, 0.f, 0.f, 0.f);
    int i = s;
    for (; i + 1 < e; i += 2) {
        int r0 = adj[i], r1 = adj[i + 1];
        float4 v0 = h4tof4(yh[(size_t)r0 * 32 + l]);
        float4 v1 = h4tof4(yh[(size_t)r1 * 32 + l]);
        a0.x += v0.x; a0.y += v0.y; a0.z += v0.z; a0.w += v0.w;
        a1.x += v1.x; a1.y += v1.y; a1.z += v1.z; a1.w += v1.w;
    }
    if (i < e) {
        float4 v0 = h4tof4(yh[(size_t)adj[i] * 32 + l]);
        a0.x += v0.x; a0.y += v0.y; a0.z += v0.z; a0.w += v0.w;
    }
    half4v o;
    o.a = __floats2half2_rn(a0.x + a1.x, a0.y + a1.y);
    o.b = __floats2half2_rn(a0.z + a1.z, a0.w + a1.w);
    agg2[(size_t)n * 32 + l] = o;
}

// sums[g][d] = sum over nodes of relu(dinv[n]*agg2[n][d] + b[d])
__global__ __launch_bounds__(128) void k_pool(const __half* __restrict__ agg2, const float* __restrict__ dinv,
                                              const float* __restrict__ b, const int* __restrict__ start,
                                              float* __restrict__ sums) {
    int g = blockIdx.x / CH, q = blockIdx.x % CH;
    int d = threadIdx.x;
    int s = start[g], e = start[g + 1];
    int len = e - s;
    int n0 = s + (int)((long)len * q / CH);
    int n1 = s + (int)((long)len * (q + 1) / CH);
    float bias = b[d];
    float acc = 0.f;
    for (int n = n0; n < n1; ++n) {
        float v = dinv[n] * __half2float(agg2[(size_t)n * DIM + d]) + bias;
        acc += fmaxf(v, 0.f);
    }
    atomicAdd(&sums[g * DIM + d], acc);
}

// xg[t][j] = b_ih[j] + b_hh[j] + pooled[t] . w_ih[j]
__global__ __launch_bounds__(512) void k_xgate(const float* __restrict__ sums, const int* __restrict__ start,
                                               const float* __restrict__ w_ih, const float* __restrict__ b_ih,
                                               const float* __restrict__ b_hh, float* __restrict__ xg) {
    __shared__ float4 p4[DIM / 4];
    int t = blockIdx.x, j = threadIdx.x;
    if (j < DIM) {
        int c = start[t + 1] - start[t];
        float inv = 1.0f / fmaxf((float)c, 1.0f);
        ((float*)p4)[j] = sums[t * DIM + j] * inv;
    }
    __syncthreads();
    const float4* w4 = (const float4*)(w_ih + (size_t)j * DIM);
    float acc = b_ih[j] + b_hh[j];
#pragma unroll
    for (int kk = 0; kk < 32; ++kk) {
        float4 w = w4[kk];
        float4 p = p4[kk];
        acc += w.x * p.x + w.y * p.y + w.z * p.z + w.w * p.w;
    }
    xg[t * GATE + j] = acc;
}

// sequential LSTM recurrence + final FC, single block
__global__ __launch_bounds__(1024) void k_lstm(const float* __restrict__ xg, const float* __restrict__ w_hh,
                                               const float* __restrict__ Wfc, const float* __restrict__ bfc,
                                               float* __restrict__ out) {
    __shared__ float h_lds[DIM];
    __shared__ float gates[GATE];
    __shared__ float hs[NG * DIM];  // 32 KB
    int tid = threadIdx.x;
    int j = tid >> 1, half = tid & 1;

    float4 wv[16];
    const float4* w4 = (const float4*)(w_hh + (size_t)j * DIM + half * 64);
#pragma unroll
    for (int kk = 0; kk < 16; ++kk) wv[kk] = w4[kk];

    float c = 0.f;
    if (tid < DIM) h_lds[tid] = 0.f;
    __syncthreads();

    const float4* h4 = (const float4*)h_lds;
    for (int t = 0; t < NG; ++t) {
        float acc = (half == 0) ? xg[t * GATE + j] : 0.f;
#pragma unroll
        for (int kk = 0; kk < 16; ++kk) {
            float4 hv = h4[half * 16 + kk];
            float4 w = wv[kk];
            acc += w.x * hv.x + w.y * hv.y + w.z * hv.z + w.w * hv.w;
        }
        acc += __shfl_xor(acc, 1, 64);
        if (half == 0) gates[j] = acc;
        __syncthreads();
        if (tid < DIM) {
            float gi = gates[tid], gf = gates[DIM + tid], gg = gates[2 * DIM + tid], go = gates[3 * DIM + tid];
            c = sigf(gf) * c + sigf(gi) * tanhfast(gg);
            float hn = sigf(go) * tanhfast(c);
            h_lds[tid] = hn;
            hs[t * DIM + tid] = hn;
        }
        __syncthreads();
    }

    if (tid < NG * 10) {
        int t = tid / 10, cls = tid - t * 10;
        const float4* hv4 = (const float4*)(hs + t * DIM);
        const float4* wf4 = (const float4*)(Wfc + cls * DIM);
        float acc = bfc[cls];
#pragma unroll
        for (int kk = 0; kk < 32; ++kk) {
            float4 h = hv4[kk];
            float4 w = wf4[kk];
            acc += h.x * w.x + h.y * w.y + h.z * w.z + h.w * w.w;
        }
        out[tid] = acc;
    }
}

extern "C" void kernel_launch(void* const* d_in, const int* in_sizes, int n_in,
                              void* d_out, int out_size, void* d_ws, size_t ws_size,
                              hipStream_t stream) {
    const float* x     = (const float*)d_in[0];
    const int*   ei    = (const int*)d_in[1];
    const int*   batch = (const int*)d_in[2];
    const float* W_gcn = (const float*)d_in[3];
    const float* b_gcn = (const float*)d_in[4];
    const float* w_ih  = (const float*)d_in[5];
    const float* w_hh  = (const float*)d_in[6];
    const float* b_ih  = (const float*)d_in[7];
    const float* b_hh  = (const float*)d_in[8];
    const float* W_fc  = (const float*)d_in[9];
    const float* b_fc  = (const float*)d_in[10];
    float* out = (float*)d_out;

    char* ws = (char*)d_ws;
    half4v* yh    = (half4v*)ws;                                   // 25.6 MB
    half4v* agg2  = (half4v*)(ws + (size_t)NNODES * DIM * 2);      // 25.6 MB
    float*  dinv  = (float*)(ws + (size_t)NNODES * DIM * 4);       // 400 KB
    float*  sums  = dinv + 100096;
    float*  xg    = sums + NG * DIM;
    int*    deg   = (int*)(xg + NG * GATE);
    int*    row_ptr = deg + 100096;
    int*    cursor  = row_ptr + 100096;
    int*    adj     = cursor + 100096;      // 6.4 MB
    int*    start   = adj + NEDGES;
    int*    bsum    = start + 128;

    hipMemsetAsync(deg, 0, NNODES * sizeof(int), stream);
    hipMemsetAsync(sums, 0, NG * DIM * sizeof(float), stream);

    k_deg<<<(NEDGES + 255) / 256, 256, 0, stream>>>(ei, deg);
    k_scan1<<<SCAN_NB, 1024, 0, stream>>>(deg, row_ptr, bsum);
    k_scan2<<<1, 128, 0, stream>>>(bsum, row_ptr, batch, start);
    k_scan3<<<SCAN_NB, 1024, 0, stream>>>(deg, row_ptr, bsum, cursor, dinv);
    k_fill<<<(NEDGES + 255) / 256, 256, 0, stream>>>(ei, cursor, adj);
    k_gemm<<<(NNODES + 63) / 64, 256, 0, stream>>>(x, W_gcn, dinv, yh);
    k_gather<<<(NNODES + 7) / 8, 256, 0, stream>>>(row_ptr, adj, yh, agg2);
    k_pool<<<NG * CH, 128, 0, stream>>>((const __half*)agg2, dinv, b_gcn, start, sums);
    k_xgate<<<NG, 512, 0, stream>>>(sums, start, w_ih, b_ih, b_hh, xg);
    k_lstm<<<1, 1024, 0, stream>>>(xg, w_hh, W_fc, b_fc, out);
}

// Round 5
// 482.414 us; speedup vs baseline: 6.2032x; 1.0487x over previous
//
#include <hip/hip_runtime.h>
#include <hip/hip_fp16.h>
#include <math.h>

#define NNODES 100000
#define NEDGES 1600000
#define DIM 128
#define NG 64
#define GATE 512
#define CH 16
#define SCAN_NB 98  // ceil(NNODES / 1024)
#define FILL_NPASS 4
#define BUCKET ((NNODES + FILL_NPASS - 1) / FILL_NPASS)  // 25000

struct alignas(8) half4v { __half2 a, b; };

__device__ __forceinline__ float sigf(float x) { return 1.0f / (1.0f + __expf(-x)); }
__device__ __forceinline__ float tanhfast(float x) {
    float e = __expf(2.0f * x);
    return 1.0f - 2.0f / (e + 1.0f);
}
__device__ __forceinline__ float4 h4tof4(half4v v) {
    float2 p = __half22float2(v.a);
    float2 q = __half22float2(v.b);
    return make_float4(p.x, p.y, q.x, q.y);
}

// in-degree count by col (int atomics)
__global__ __launch_bounds__(256) void k_deg(const int* __restrict__ ei, int* __restrict__ deg) {
    int e = blockIdx.x * 256 + threadIdx.x;
    if (e < NEDGES) atomicAdd(&deg[ei[NEDGES + e]], 1);
}

// stage 1: per-block exclusive scan of deg; block sums out
__global__ __launch_bounds__(1024) void k_scan1(const int* __restrict__ deg, int* __restrict__ row_ptr,
                                                int* __restrict__ bsum) {
    __shared__ int ls[1024];
    int tid = threadIdx.x;
    int n = blockIdx.x * 1024 + tid;
    int v = (n < NNODES) ? deg[n] : 0;
    ls[tid] = v;
    __syncthreads();
    for (int off = 1; off < 1024; off <<= 1) {
        int t = (tid >= off) ? ls[tid - off] : 0;
        __syncthreads();
        ls[tid] += t;
        __syncthreads();
    }
    if (n < NNODES) row_ptr[n] = ls[tid] - v;  // exclusive within block
    if (tid == 1023) bsum[blockIdx.x] = ls[1023];
}

// stage 2: exclusive scan of block sums + graph segment bounds (batch sorted)
__global__ __launch_bounds__(128) void k_scan2(int* __restrict__ bsum, int* __restrict__ row_ptr,
                                               const int* __restrict__ batch, int* __restrict__ start) {
    __shared__ int ls[128];
    int tid = threadIdx.x;
    int v = (tid < SCAN_NB) ? bsum[tid] : 0;
    ls[tid] = v;
    __syncthreads();
    for (int off = 1; off < 128; off <<= 1) {
        int t = (tid >= off) ? ls[tid - off] : 0;
        __syncthreads();
        ls[tid] += t;
        __syncthreads();
    }
    if (tid < SCAN_NB) bsum[tid] = ls[tid] - v;  // exclusive block offsets
    if (tid == 127) row_ptr[NNODES] = ls[127];
    // graph bounds via binary search
    if (tid <= NG) {
        int lo = 0, hi = NNODES;
        while (lo < hi) {
            int mid = (lo + hi) >> 1;
            if (batch[mid] < tid) lo = mid + 1; else hi = mid;
        }
        start[tid] = lo;
    }
}

// stage 3: add block offsets; init cursor = row_ptr; compute dinv
__global__ __launch_bounds__(1024) void k_scan3(const int* __restrict__ deg, int* __restrict__ row_ptr,
                                                const int* __restrict__ bsum, int* __restrict__ cursor,
                                                float* __restrict__ dinv) {
    int n = blockIdx.x * 1024 + threadIdx.x;
    if (n < NNODES) {
        int rp = row_ptr[n] + bsum[blockIdx.x];
        row_ptr[n] = rp;
        cursor[n] = rp;
        dinv[n] = rsqrtf((float)deg[n] + 1.0f);
    }
}

// adj[cursor[col]++] = row, only for cols in [b0, b0+BUCKET): temporal
// bucketing keeps the adj write window at 1.6 MB -> lines fill in L2
__global__ __launch_bounds__(256) void k_fillb(const int* __restrict__ ei, int* __restrict__ cursor,
                                               int* __restrict__ adj, int b0) {
    int e = blockIdx.x * 256 + threadIdx.x;
    if (e < NEDGES) {
        int col = ei[NEDGES + e];
        if (col >= b0 && col < b0 + BUCKET) {
            int row = ei[e];
            int pos = atomicAdd(&cursor[col], 1);
            adj[pos] = row;
        }
    }
}

// y[n] = (x[n] @ W) * dinv[n], stored fp16
__global__ __launch_bounds__(256) void k_gemm(const float* __restrict__ x, const float* __restrict__ W,
                                              const float* __restrict__ dinv, half4v* __restrict__ yh) {
    __shared__ float4 Wl[DIM * DIM / 4];  // 64 KB
    const float4* W4 = (const float4*)W;
    int tid = threadIdx.x;
#pragma unroll
    for (int l = 0; l < 16; ++l) Wl[tid + l * 256] = W4[tid + l * 256];
    __syncthreads();

    int tr = tid >> 5, tc = tid & 31;
    int rb = blockIdx.x * 64;
    const float4* x4 = (const float4*)x;

    int r[8];
    bool valid[8];
#pragma unroll
    for (int i = 0; i < 8; ++i) {
        int rr = rb + tr * 8 + i;
        valid[i] = rr < NNODES;
        r[i] = valid[i] ? rr : (NNODES - 1);
    }

    float4 acc[8];
#pragma unroll
    for (int i = 0; i < 8; ++i) acc[i] = make_float4(0.f, 0.f, 0.f, 0.f);

    for (int k = 0; k < DIM; k += 4) {
        float4 wv[4];
#pragma unroll
        for (int kk = 0; kk < 4; ++kk) wv[kk] = Wl[(k + kk) * 32 + tc];
#pragma unroll
        for (int i = 0; i < 8; ++i) {
            float4 xv = x4[(size_t)r[i] * 32 + (k >> 2)];
            acc[i].x += xv.x * wv[0].x + xv.y * wv[1].x + xv.z * wv[2].x + xv.w * wv[3].x;
            acc[i].y += xv.x * wv[0].y + xv.y * wv[1].y + xv.z * wv[2].y + xv.w * wv[3].y;
            acc[i].z += xv.x * wv[0].z + xv.y * wv[1].z + xv.z * wv[2].z + xv.w * wv[3].z;
            acc[i].w += xv.x * wv[0].w + xv.y * wv[1].w + xv.z * wv[2].w + xv.w * wv[3].w;
        }
    }

#pragma unroll
    for (int i = 0; i < 8; ++i) {
        if (valid[i]) {
            float dv = dinv[r[i]];
            half4v v;
            v.a = __floats2half2_rn(acc[i].x * dv, acc[i].y * dv);
            v.b = __floats2half2_rn(acc[i].z * dv, acc[i].w * dv);
            yh[(size_t)r[i] * 32 + tc] = v;
        }
    }
}

// agg2[n] = y[n] + sum over in-neighbors y[row]  (CSR gather, fp16 in/out, f32 accum)
__global__ __launch_bounds__(256) void k_gather(const int* __restrict__ row_ptr, const int* __restrict__ adj,
                                                const half4v* __restrict__ yh, half4v* __restrict__ agg2) {
    int grp = threadIdx.x >> 5;  // 8 nodes per block
    int l = threadIdx.x & 31;    // 32 lanes x 4 dims = 128 dims
    int n = blockIdx.x * 8 + grp;
    if (n >= NNODES) return;
    int s = row_ptr[n], e = row_ptr[n + 1];
    float4 a0 = h4tof4(yh[(size_t)n * 32 + l]);  // self-loop term
    float4 a1 = make_float4(0.f, 0.f, 0.f, 0.f);
    int i = s;
    for (; i + 1 < e; i += 2) {
        int r0 = adj[i], r1 = adj[i + 1];
        float4 v0 = h4tof4(yh[(size_t)r0 * 32 + l]);
        float4 v1 = h4tof4(yh[(size_t)r1 * 32 + l]);
        a0.x += v0.x; a0.y += v0.y; a0.z += v0.z; a0.w += v0.w;
        a1.x += v1.x; a1.y += v1.y; a1.z += v1.z; a1.w += v1.w;
    }
    if (i < e) {
        float4 v0 = h4tof4(yh[(size_t)adj[i] * 32 + l]);
        a0.x += v0.x; a0.y += v0.y; a0.z += v0.z; a0.w += v0.w;
    }
    half4v o;
    o.a = __floats2half2_rn(a0.x + a1.x, a0.y + a1.y);
    o.b = __floats2half2_rn(a0.z + a1.z, a0.w + a1.w);
    agg2[(size_t)n * 32 + l] = o;
}

// sums[g][d] = sum over nodes of relu(dinv[n]*agg2[n][d] + b[d])
__global__ __launch_bounds__(128) void k_pool(const __half* __restrict__ agg2, const float* __restrict__ dinv,
                                              const float* __restrict__ b, const int* __restrict__ start,
                                              float* __restrict__ sums) {
    int g = blockIdx.x / CH, q = blockIdx.x % CH;
    int d = threadIdx.x;
    int s = start[g], e = start[g + 1];
    int len = e - s;
    int n0 = s + (int)((long)len * q / CH);
    int n1 = s + (int)((long)len * (q + 1) / CH);
    float bias = b[d];
    float acc = 0.f;
    for (int n = n0; n < n1; ++n) {
        float v = dinv[n] * __half2float(agg2[(size_t)n * DIM + d]) + bias;
        acc += fmaxf(v, 0.f);
    }
    atomicAdd(&sums[g * DIM + d], acc);
}

// xg[t][j] = b_ih[j] + b_hh[j] + pooled[t] . w_ih[j]
__global__ __launch_bounds__(512) void k_xgate(const float* __restrict__ sums, const int* __restrict__ start,
                                               const float* __restrict__ w_ih, const float* __restrict__ b_ih,
                                               const float* __restrict__ b_hh, float* __restrict__ xg) {
    __shared__ float4 p4[DIM / 4];
    int t = blockIdx.x, j = threadIdx.x;
    if (j < DIM) {
        int c = start[t + 1] - start[t];
        float inv = 1.0f / fmaxf((float)c, 1.0f);
        ((float*)p4)[j] = sums[t * DIM + j] * inv;
    }
    __syncthreads();
    const float4* w4 = (const float4*)(w_ih + (size_t)j * DIM);
    float acc = b_ih[j] + b_hh[j];
#pragma unroll
    for (int kk = 0; kk < 32; ++kk) {
        float4 w = w4[kk];
        float4 p = p4[kk];
        acc += w.x * p.x + w.y * p.y + w.z * p.z + w.w * p.w;
    }
    xg[t * GATE + j] = acc;
}

// sequential LSTM recurrence + final FC, single block
__global__ __launch_bounds__(1024) void k_lstm(const float* __restrict__ xg, const float* __restrict__ w_hh,
                                               const float* __restrict__ Wfc, const float* __restrict__ bfc,
                                               float* __restrict__ out) {
    __shared__ float h_lds[DIM];
    __shared__ float gates[GATE];
    __shared__ float hs[NG * DIM];  // 32 KB
    int tid = threadIdx.x;
    int j = tid >> 1, half = tid & 1;

    float4 wv[16];
    const float4* w4 = (const float4*)(w_hh + (size_t)j * DIM + half * 64);
#pragma unroll
    for (int kk = 0; kk < 16; ++kk) wv[kk] = w4[kk];

    float c = 0.f;
    if (tid < DIM) h_lds[tid] = 0.f;
    __syncthreads();

    const float4* h4 = (const float4*)h_lds;
    for (int t = 0; t < NG; ++t) {
        float acc = (half == 0) ? xg[t * GATE + j] : 0.f;
#pragma unroll
        for (int kk = 0; kk < 16; ++kk) {
            float4 hv = h4[half * 16 + kk];
            float4 w = wv[kk];
            acc += w.x * hv.x + w.y * hv.y + w.z * hv.z + w.w * hv.w;
        }
        acc += __shfl_xor(acc, 1, 64);
        if (half == 0) gates[j] = acc;
        __syncthreads();
        if (tid < DIM) {
            float gi = gates[tid], gf = gates[DIM + tid], gg = gates[2 * DIM + tid], go = gates[3 * DIM + tid];
            c = sigf(gf) * c + sigf(gi) * tanhfast(gg);
            float hn = sigf(go) * tanhfast(c);
            h_lds[tid] = hn;
            hs[t * DIM + tid] = hn;
        }
        __syncthreads();
    }

    if (tid < NG * 10) {
        int t = tid / 10, cls = tid - t * 10;
        const float4* hv4 = (const float4*)(hs + t * DIM);
        const float4* wf4 = (const float4*)(Wfc + cls * DIM);
        float acc = bfc[cls];
#pragma unroll
        for (int kk = 0; kk < 32; ++kk) {
            float4 h = hv4[kk];
            float4 w = wf4[kk];
            acc += h.x * w.x + h.y * w.y + h.z * w.z + h.w * w.w;
        }
        out[tid] = acc;
    }
}

extern "C" void kernel_launch(void* const* d_in, const int* in_sizes, int n_in,
                              void* d_out, int out_size, void* d_ws, size_t ws_size,
                              hipStream_t stream) {
    const float* x     = (const float*)d_in[0];
    const int*   ei    = (const int*)d_in[1];
    const int*   batch = (const int*)d_in[2];
    const float* W_gcn = (const float*)d_in[3];
    const float* b_gcn = (const float*)d_in[4];
    const float* w_ih  = (const float*)d_in[5];
    const float* w_hh  = (const float*)d_in[6];
    const float* b_ih  = (const float*)d_in[7];
    const float* b_hh  = (const float*)d_in[8];
    const float* W_fc  = (const float*)d_in[9];
    const float* b_fc  = (const float*)d_in[10];
    float* out = (float*)d_out;

    char* ws = (char*)d_ws;
    half4v* yh    = (half4v*)ws;                                   // 25.6 MB
    half4v* agg2  = (half4v*)(ws + (size_t)NNODES * DIM * 2);      // 25.6 MB
    float*  dinv  = (float*)(ws + (size_t)NNODES * DIM * 4);       // 400 KB
    float*  sums  = dinv + 100096;
    float*  xg    = sums + NG * DIM;
    int*    deg   = (int*)(xg + NG * GATE);
    int*    row_ptr = deg + 100096;
    int*    cursor  = row_ptr + 100096;
    int*    adj     = cursor + 100096;      // 6.4 MB
    int*    start   = adj + NEDGES;
    int*    bsum    = start + 128;

    hipMemsetAsync(deg, 0, NNODES * sizeof(int), stream);
    hipMemsetAsync(sums, 0, NG * DIM * sizeof(float), stream);

    k_deg<<<(NEDGES + 255) / 256, 256, 0, stream>>>(ei, deg);
    k_scan1<<<SCAN_NB, 1024, 0, stream>>>(deg, row_ptr, bsum);
    k_scan2<<<1, 128, 0, stream>>>(bsum, row_ptr, batch, start);
    k_scan3<<<SCAN_NB, 1024, 0, stream>>>(deg, row_ptr, bsum, cursor, dinv);
    for (int p = 0; p < FILL_NPASS; ++p)
        k_fillb<<<(NEDGES + 255) / 256, 256, 0, stream>>>(ei, cursor, adj, p * BUCKET);
    k_gemm<<<(NNODES + 63) / 64, 256, 0, stream>>>(x, W_gcn, dinv, yh);
    k_gather<<<(NNODES + 7) / 8, 256, 0, stream>>>(row_ptr, adj, yh, agg2);
    k_pool<<<NG * CH, 128, 0, stream>>>((const __half*)agg2, dinv, b_gcn, start, sums);
    k_xgate<<<NG, 512, 0, stream>>>(sums, start, w_ih, b_ih, b_hh, xg);
    k_lstm<<<1, 1024, 0, stream>>>(xg, w_hh, W_fc, b_fc, out);
}

// Round 6
// 479.613 us; speedup vs baseline: 6.2394x; 1.0058x over previous
//
#include <hip/hip_runtime.h>
#include <hip/hip_fp16.h>
#include <math.h>

#define NNODES 100000
#define NEDGES 1600000
#define DIM 128
#define NG 64
#define GATE 512
#define CH 16
#define SCAN_NB 98  // ceil(NNODES / 1024)
#define FILL_NPASS 4
#define BUCKET ((NNODES + FILL_NPASS - 1) / FILL_NPASS)  // 25000

struct alignas(8) half4v { __half2 a, b; };

// fast sigmoid/tanh: v_exp_f32 + v_rcp_f32 (absmax headroom is ~100x)
__device__ __forceinline__ float sigf(float x) {
    return __builtin_amdgcn_rcpf(1.0f + __expf(-x));
}
__device__ __forceinline__ float tanhfast(float x) {
    float e = __expf(2.0f * x);
    return 1.0f - 2.0f * __builtin_amdgcn_rcpf(e + 1.0f);
}
__device__ __forceinline__ float4 h4tof4(half4v v) {
    float2 p = __half22float2(v.a);
    float2 q = __half22float2(v.b);
    return make_float4(p.x, p.y, q.x, q.y);
}

// in-degree count by col (int atomics)
__global__ __launch_bounds__(256) void k_deg(const int* __restrict__ ei, int* __restrict__ deg) {
    int e = blockIdx.x * 256 + threadIdx.x;
    if (e < NEDGES) atomicAdd(&deg[ei[NEDGES + e]], 1);
}

// stage 1: per-block exclusive scan of deg; block sums out
__global__ __launch_bounds__(1024) void k_scan1(const int* __restrict__ deg, int* __restrict__ row_ptr,
                                                int* __restrict__ bsum) {
    __shared__ int ls[1024];
    int tid = threadIdx.x;
    int n = blockIdx.x * 1024 + tid;
    int v = (n < NNODES) ? deg[n] : 0;
    ls[tid] = v;
    __syncthreads();
    for (int off = 1; off < 1024; off <<= 1) {
        int t = (tid >= off) ? ls[tid - off] : 0;
        __syncthreads();
        ls[tid] += t;
        __syncthreads();
    }
    if (n < NNODES) row_ptr[n] = ls[tid] - v;  // exclusive within block
    if (tid == 1023) bsum[blockIdx.x] = ls[1023];
}

// stage 2: exclusive scan of block sums + graph segment bounds (batch sorted)
__global__ __launch_bounds__(128) void k_scan2(int* __restrict__ bsum, int* __restrict__ row_ptr,
                                               const int* __restrict__ batch, int* __restrict__ start) {
    __shared__ int ls[128];
    int tid = threadIdx.x;
    int v = (tid < SCAN_NB) ? bsum[tid] : 0;
    ls[tid] = v;
    __syncthreads();
    for (int off = 1; off < 128; off <<= 1) {
        int t = (tid >= off) ? ls[tid - off] : 0;
        __syncthreads();
        ls[tid] += t;
        __syncthreads();
    }
    if (tid < SCAN_NB) bsum[tid] = ls[tid] - v;  // exclusive block offsets
    if (tid == 127) row_ptr[NNODES] = ls[127];
    // graph bounds via binary search
    if (tid <= NG) {
        int lo = 0, hi = NNODES;
        while (lo < hi) {
            int mid = (lo + hi) >> 1;
            if (batch[mid] < tid) lo = mid + 1; else hi = mid;
        }
        start[tid] = lo;
    }
}

// stage 3: add block offsets; init cursor = row_ptr; compute dinv
__global__ __launch_bounds__(1024) void k_scan3(const int* __restrict__ deg, int* __restrict__ row_ptr,
                                                const int* __restrict__ bsum, int* __restrict__ cursor,
                                                float* __restrict__ dinv) {
    int n = blockIdx.x * 1024 + threadIdx.x;
    if (n < NNODES) {
        int rp = row_ptr[n] + bsum[blockIdx.x];
        row_ptr[n] = rp;
        cursor[n] = rp;
        dinv[n] = rsqrtf((float)deg[n] + 1.0f);
    }
}

// adj[cursor[col]++] = row, only for cols in [b0, b0+BUCKET): temporal
// bucketing keeps the adj write window at 1.6 MB -> lines fill in L2
__global__ __launch_bounds__(256) void k_fillb(const int* __restrict__ ei, int* __restrict__ cursor,
                                               int* __restrict__ adj, int b0) {
    int e = blockIdx.x * 256 + threadIdx.x;
    if (e < NEDGES) {
        int col = ei[NEDGES + e];
        if (col >= b0 && col < b0 + BUCKET) {
            int row = ei[e];
            int pos = atomicAdd(&cursor[col], 1);
            adj[pos] = row;
        }
    }
}

// y[n] = (x[n] @ W) * dinv[n], stored fp16
__global__ __launch_bounds__(256) void k_gemm(const float* __restrict__ x, const float* __restrict__ W,
                                              const float* __restrict__ dinv, half4v* __restrict__ yh) {
    __shared__ float4 Wl[DIM * DIM / 4];  // 64 KB
    const float4* W4 = (const float4*)W;
    int tid = threadIdx.x;
#pragma unroll
    for (int l = 0; l < 16; ++l) Wl[tid + l * 256] = W4[tid + l * 256];
    __syncthreads();

    int tr = tid >> 5, tc = tid & 31;
    int rb = blockIdx.x * 64;
    const float4* x4 = (const float4*)x;

    int r[8];
    bool valid[8];
#pragma unroll
    for (int i = 0; i < 8; ++i) {
        int rr = rb + tr * 8 + i;
        valid[i] = rr < NNODES;
        r[i] = valid[i] ? rr : (NNODES - 1);
    }

    float4 acc[8];
#pragma unroll
    for (int i = 0; i < 8; ++i) acc[i] = make_float4(0.f, 0.f, 0.f, 0.f);

    for (int k = 0; k < DIM; k += 4) {
        float4 wv[4];
#pragma unroll
        for (int kk = 0; kk < 4; ++kk) wv[kk] = Wl[(k + kk) * 32 + tc];
#pragma unroll
        for (int i = 0; i < 8; ++i) {
            float4 xv = x4[(size_t)r[i] * 32 + (k >> 2)];
            acc[i].x += xv.x * wv[0].x + xv.y * wv[1].x + xv.z * wv[2].x + xv.w * wv[3].x;
            acc[i].y += xv.x * wv[0].y + xv.y * wv[1].y + xv.z * wv[2].y + xv.w * wv[3].y;
            acc[i].z += xv.x * wv[0].z + xv.y * wv[1].z + xv.z * wv[2].z + xv.w * wv[3].z;
            acc[i].w += xv.x * wv[0].w + xv.y * wv[1].w + xv.z * wv[2].w + xv.w * wv[3].w;
        }
    }

#pragma unroll
    for (int i = 0; i < 8; ++i) {
        if (valid[i]) {
            float dv = dinv[r[i]];
            half4v v;
            v.a = __floats2half2_rn(acc[i].x * dv, acc[i].y * dv);
            v.b = __floats2half2_rn(acc[i].z * dv, acc[i].w * dv);
            yh[(size_t)r[i] * 32 + tc] = v;
        }
    }
}

// agg2[n] = y[n] + sum over in-neighbors y[row]  (CSR gather, fp16 in/out, f32 accum)
__global__ __launch_bounds__(256) void k_gather(const int* __restrict__ row_ptr, const int* __restrict__ adj,
                                                const half4v* __restrict__ yh, half4v* __restrict__ agg2) {
    int grp = threadIdx.x >> 5;  // 8 nodes per block
    int l = threadIdx.x & 31;    // 32 lanes x 4 dims = 128 dims
    int n = blockIdx.x * 8 + grp;
    if (n >= NNODES) return;
    int s = row_ptr[n], e = row_ptr[n + 1];
    float4 a0 = h4tof4(yh[(size_t)n * 32 + l]);  // self-loop term
    float4 a1 = make_float4(0.f, 0.f, 0.f, 0.f);
    int i = s;
    for (; i + 1 < e; i += 2) {
        int r0 = adj[i], r1 = adj[i + 1];
        float4 v0 = h4tof4(yh[(size_t)r0 * 32 + l]);
        float4 v1 = h4tof4(yh[(size_t)r1 * 32 + l]);
        a0.x += v0.x; a0.y += v0.y; a0.z += v0.z; a0.w += v0.w;
        a1.x += v1.x; a1.y += v1.y; a1.z += v1.z; a1.w += v1.w;
    }
    if (i < e) {
        float4 v0 = h4tof4(yh[(size_t)adj[i] * 32 + l]);
        a0.x += v0.x; a0.y += v0.y; a0.z += v0.z; a0.w += v0.w;
    }
    half4v o;
    o.a = __floats2half2_rn(a0.x + a1.x, a0.y + a1.y);
    o.b = __floats2half2_rn(a0.z + a1.z, a0.w + a1.w);
    agg2[(size_t)n * 32 + l] = o;
}

// sums[g][d] = sum over nodes of relu(dinv[n]*agg2[n][d] + b[d])
__global__ __launch_bounds__(128) void k_pool(const __half* __restrict__ agg2, const float* __restrict__ dinv,
                                              const float* __restrict__ b, const int* __restrict__ start,
                                              float* __restrict__ sums) {
    int g = blockIdx.x / CH, q = blockIdx.x % CH;
    int d = threadIdx.x;
    int s = start[g], e = start[g + 1];
    int len = e - s;
    int n0 = s + (int)((long)len * q / CH);
    int n1 = s + (int)((long)len * (q + 1) / CH);
    float bias = b[d];
    float acc = 0.f;
    for (int n = n0; n < n1; ++n) {
        float v = dinv[n] * __half2float(agg2[(size_t)n * DIM + d]) + bias;
        acc += fmaxf(v, 0.f);
    }
    atomicAdd(&sums[g * DIM + d], acc);
}

// xg[t][j] = b_ih[j] + b_hh[j] + pooled[t] . w_ih[j]
__global__ __launch_bounds__(512) void k_xgate(const float* __restrict__ sums, const int* __restrict__ start,
                                               const float* __restrict__ w_ih, const float* __restrict__ b_ih,
                                               const float* __restrict__ b_hh, float* __restrict__ xg) {
    __shared__ float4 p4[DIM / 4];
    int t = blockIdx.x, j = threadIdx.x;
    if (j < DIM) {
        int c = start[t + 1] - start[t];
        float inv = 1.0f / fmaxf((float)c, 1.0f);
        ((float*)p4)[j] = sums[t * DIM + j] * inv;
    }
    __syncthreads();
    const float4* w4 = (const float4*)(w_ih + (size_t)j * DIM);
    float acc = b_ih[j] + b_hh[j];
#pragma unroll
    for (int kk = 0; kk < 32; ++kk) {
        float4 w = w4[kk];
        float4 p = p4[kk];
        acc += w.x * p.x + w.y * p.y + w.z * p.z + w.w * p.w;
    }
    xg[t * GATE + j] = acc;
}

// sequential LSTM recurrence + final FC, single block of 512 (8 waves).
// Thread j owns gate row j: w_hh row in 32 float4 registers; h broadcast
// from LDS (lane-uniform reads -> zero bank conflicts); xg prefetched one
// step ahead to hide global latency under the FMA chain.
__global__ __launch_bounds__(512) void k_lstm(const float* __restrict__ xg, const float* __restrict__ w_hh,
                                              const float* __restrict__ Wfc, const float* __restrict__ bfc,
                                              float* __restrict__ out) {
    __shared__ float h_lds[DIM];
    __shared__ float gates[GATE];
    __shared__ float hs[NG * DIM];  // 32 KB
    int j = threadIdx.x;

    // w_hh row j in registers (128 VGPRs)
    float4 wv[32];
    const float4* w4 = (const float4*)(w_hh + (size_t)j * DIM);
#pragma unroll
    for (int kk = 0; kk < 32; ++kk) wv[kk] = w4[kk];

    float c = 0.f;
    if (j < DIM) h_lds[j] = 0.f;
    float xcur = xg[j];  // t=0 pre-activation
    __syncthreads();

    const float4* h4 = (const float4*)h_lds;
    for (int t = 0; t < NG; ++t) {
        // prefetch next step's xg early; result needed only next iteration
        float xnext = (t + 1 < NG) ? xg[(t + 1) * GATE + j] : 0.f;
        float a0 = xcur, a1 = 0.f, a2 = 0.f, a3 = 0.f;
#pragma unroll
        for (int kk = 0; kk < 32; ++kk) {
            float4 hv = h4[kk];  // lane-uniform -> LDS broadcast
            float4 w = wv[kk];
            a0 += w.x * hv.x;
            a1 += w.y * hv.y;
            a2 += w.z * hv.z;
            a3 += w.w * hv.w;
        }
        gates[j] = (a0 + a1) + (a2 + a3);
        __syncthreads();
        if (j < DIM) {
            float gi = gates[j], gf = gates[DIM + j], gg = gates[2 * DIM + j], go = gates[3 * DIM + j];
            c = sigf(gf) * c + sigf(gi) * tanhfast(gg);
            float hn = sigf(go) * tanhfast(c);
            h_lds[j] = hn;
            hs[t * DIM + j] = hn;
        }
        xcur = xnext;
        __syncthreads();
    }

    // FC: out[t][cls] = b_fc[cls] + hs[t] . W_fc[cls]
    for (int o = j; o < NG * 10; o += 512) {
        int t = o / 10, cls = o - t * 10;
        const float4* hv4 = (const float4*)(hs + t * DIM);
        const float4* wf4 = (const float4*)(Wfc + cls * DIM);
        float acc = bfc[cls];
#pragma unroll
        for (int kk = 0; kk < 32; ++kk) {
            float4 h = hv4[kk];
            float4 w = wf4[kk];
            acc += h.x * w.x + h.y * w.y + h.z * w.z + h.w * w.w;
        }
        out[o] = acc;
    }
}

extern "C" void kernel_launch(void* const* d_in, const int* in_sizes, int n_in,
                              void* d_out, int out_size, void* d_ws, size_t ws_size,
                              hipStream_t stream) {
    const float* x     = (const float*)d_in[0];
    const int*   ei    = (const int*)d_in[1];
    const int*   batch = (const int*)d_in[2];
    const float* W_gcn = (const float*)d_in[3];
    const float* b_gcn = (const float*)d_in[4];
    const float* w_ih  = (const float*)d_in[5];
    const float* w_hh  = (const float*)d_in[6];
    const float* b_ih  = (const float*)d_in[7];
    const float* b_hh  = (const float*)d_in[8];
    const float* W_fc  = (const float*)d_in[9];
    const float* b_fc  = (const float*)d_in[10];
    float* out = (float*)d_out;

    char* ws = (char*)d_ws;
    half4v* yh    = (half4v*)ws;                                   // 25.6 MB
    half4v* agg2  = (half4v*)(ws + (size_t)NNODES * DIM * 2);      // 25.6 MB
    float*  dinv  = (float*)(ws + (size_t)NNODES * DIM * 4);       // 400 KB
    float*  sums  = dinv + 100096;
    float*  xg    = sums + NG * DIM;
    int*    deg   = (int*)(xg + NG * GATE);
    int*    row_ptr = deg + 100096;
    int*    cursor  = row_ptr + 100096;
    int*    adj     = cursor + 100096;      // 6.4 MB
    int*    start   = adj + NEDGES;
    int*    bsum    = start + 128;

    hipMemsetAsync(deg, 0, NNODES * sizeof(int), stream);
    hipMemsetAsync(sums, 0, NG * DIM * sizeof(float), stream);

    k_deg<<<(NEDGES + 255) / 256, 256, 0, stream>>>(ei, deg);
    k_scan1<<<SCAN_NB, 1024, 0, stream>>>(deg, row_ptr, bsum);
    k_scan2<<<1, 128, 0, stream>>>(bsum, row_ptr, batch, start);
    k_scan3<<<SCAN_NB, 1024, 0, stream>>>(deg, row_ptr, bsum, cursor, dinv);
    for (int p = 0; p < FILL_NPASS; ++p)
        k_fillb<<<(NEDGES + 255) / 256, 256, 0, stream>>>(ei, cursor, adj, p * BUCKET);
    k_gemm<<<(NNODES + 63) / 64, 256, 0, stream>>>(x, W_gcn, dinv, yh);
    k_gather<<<(NNODES + 7) / 8, 256, 0, stream>>>(row_ptr, adj, yh, agg2);
    k_pool<<<NG * CH, 128, 0, stream>>>((const __half*)agg2, dinv, b_gcn, start, sums);
    k_xgate<<<NG, 512, 0, stream>>>(sums, start, w_ih, b_ih, b_hh, xg);
    k_lstm<<<1, 512, 0, stream>>>(xg, w_hh, W_fc, b_fc, out);
}